// Round 2
// baseline (1716.826 us; speedup 1.0000x reference)
//
#include <hip/hip_runtime.h>
#include <math.h>

#define BB 32
#define NN 16384
#define GG 128
#define KK 64
#define HH 128
#define DD 384
#define LN_EPS 1e-5f
#define NBUCK 2048
#define CANDCAP 1024

// round-to-nearest sum of 3 squares, matching jnp.sum(x**2, -1) order, no FMA contraction
__device__ __forceinline__ float sq3(float x, float y, float z) {
    return __fadd_rn(__fadd_rn(__fmul_rn(x, x), __fmul_rn(y, y)), __fmul_rn(z, z));
}

// order-preserving uint key of dist2, same formula/rounding as reference
__device__ __forceinline__ unsigned distkey(float px, float py, float pz, float4 c4) {
    float p2 = sq3(px, py, pz);
    float dot = __fadd_rn(__fadd_rn(__fmul_rn(c4.x, px), __fmul_rn(c4.y, py)),
                          __fmul_rn(c4.z, pz));
    float d = __fsub_rn(__fadd_rn(c4.w, p2), __fmul_rn(2.0f, dot));
    unsigned u = __float_as_uint(d);
    return u ^ ((u & 0x80000000u) ? 0xFFFFFFFFu : 0x80000000u);
}

// ---------------- prep: transpose w2 [128,384] -> w2t [384,128]; zero progress flags
__global__ void prep_kernel(const float* __restrict__ w2, float* __restrict__ w2t,
                            unsigned* __restrict__ prog) {
    int i = blockIdx.x * 256 + threadIdx.x;  // over DD*HH = 49152
    if (i < HH * DD) {
        int f = i >> 7;    // 0..383
        int k = i & 127;   // 0..127
        w2t[i] = w2[k * DD + f];
    }
    if (i < BB) prog[i] = 0;  // per-batch fps progress (centroids published)
}

// Shared-memory overlays: fps blocks and group blocks use the same union.
struct GrpSh {
    union {
        unsigned hist[2][NBUCK];              // phase 1-2 (per half)
        unsigned long long cand[2][CANDCAP];  // phase 3+ (hist dead after scan)
    } u;
    int selIdx[2][KK];
    float4 localPt[2][KK];
    float w1s[3 * HH];  // shared by both halves (read-only weights)
    float b1s[HH];
    float hbar[2][HH];
    float partial[2][256];
    float red2[2][4];
    float toks[2][DD];
    int waveSum[2][4];
    unsigned long long wmin[2][4];
    unsigned TA_S[2];
    int cntS[2];
    unsigned long long lastS[2];
    float muS[2], rstdS[2];
    float4 c4s[2];
    int fbS;
};
struct FpsSh {
    unsigned long long slot[GG];
};

// ---------------- fused kernel ----------------
// Blocks 0..31: round-0 FPS (one block per batch, 512 thr, 32 pts/thr) at wave prio 3,
// publishing per-iteration progress via relaxed agent-scope (sc1) atomics. The vmcnt(0)
// fence before each flag store is one iteration LAGGED, so it always finds the previous
// centroid's sc1 stores long-completed -> no stall on the fps critical path.
// Blocks 32..2079: two groups per block (two 256-thread halves running the proven
// group pipeline). Each half's thread 0 spin-waits (s_sleep, relaxed sc1 loads -> no
// cache invalidation) until its centroid is published, then the half proceeds.
// Grid order is g-ascending (16 blocks per g), XCD-swizzled so each XCD keeps its
// 4 batches' points (768KB) L2-resident.
// __launch_bounds__(512,6): 3 blocks/CU (24 waves), VGPR cap 85 = round-0's measured
// fps (84) and old group cap -> group throughput per CU unchanged (6 groups/CU).
__global__ __launch_bounds__(512, 6) void fused_kernel(
    const float* __restrict__ pts, const float* __restrict__ w1,
    const float* __restrict__ b1, const float* __restrict__ w2t,
    const float* __restrict__ b2, const float* __restrict__ lns,
    const float* __restrict__ lnb, float* __restrict__ cent_out,
    float4* __restrict__ cent_pad, float* __restrict__ tok_out,
    unsigned* __restrict__ prog) {
    __shared__ union {
        FpsSh f;
        GrpSh g;
    } sh;
    const int tid = threadIdx.x;

    if (blockIdx.x < BB) {
        // ================= FPS path =================
        __builtin_amdgcn_s_setprio(3);  // keep the serial producer fed under co-residency
        const int b = blockIdx.x;
        const float* p = pts + (size_t)b * NN * 3;
        const float4* p4 = (const float4*)p;

        // thread owns quads q = j*512+tid (j=0..7): points 4q..4q+3, loaded as 3 float4
        float x[32], y[32], z[32], dist[32];
#pragma unroll
        for (int j = 0; j < 8; j++) {
            int q = j * 512 + tid;
            float4 A = p4[3 * q], B = p4[3 * q + 1], C = p4[3 * q + 2];
            x[j * 4 + 0] = A.x; y[j * 4 + 0] = A.y; z[j * 4 + 0] = A.z;
            x[j * 4 + 1] = A.w; y[j * 4 + 1] = B.x; z[j * 4 + 1] = B.y;
            x[j * 4 + 2] = B.z; y[j * 4 + 2] = B.w; z[j * 4 + 2] = C.x;
            x[j * 4 + 3] = C.y; y[j * 4 + 3] = C.z; z[j * 4 + 3] = C.w;
#pragma unroll
            for (int t = 0; t < 4; t++) dist[j * 4 + t] = INFINITY;
        }

        for (int i = tid; i < GG; i += 512) sh.f.slot[i] = 0ull;
        __syncthreads();

        float cx = p[0], cy = p[1], cz = p[2];  // deterministic start at index 0

        for (int it = 0; it < GG; it++) {
            if (tid == 0) {
                if (it > 0) {
                    // previous iteration's sc1 stores are long since complete ->
                    // this wait is free; it orders them before the flag store.
                    asm volatile("s_waitcnt vmcnt(0)" ::: "memory");
                    __hip_atomic_store(&prog[b], (unsigned)it, __ATOMIC_RELAXED,
                                       __HIP_MEMORY_SCOPE_AGENT);
                }
                float* co = cent_out + ((size_t)b * GG + it) * 3;
                co[0] = cx; co[1] = cy; co[2] = cz;
                float c2v = sq3(cx, cy, cz);
                unsigned long long lo =
                    ((unsigned long long)__float_as_uint(cy) << 32) | __float_as_uint(cx);
                unsigned long long hi =
                    ((unsigned long long)__float_as_uint(c2v) << 32) | __float_as_uint(cz);
                unsigned long long* cp =
                    (unsigned long long*)&cent_pad[(size_t)b * GG + it];
                // sc1 stores: land at the coherence point so readers' sc1 loads see them
                __hip_atomic_store(cp, lo, __ATOMIC_RELAXED, __HIP_MEMORY_SCOPE_AGENT);
                __hip_atomic_store(cp + 1, hi, __ATOMIC_RELAXED, __HIP_MEMORY_SCOPE_AGENT);
            }
            if (it == GG - 1) break;  // last argmax unused

            // distance update + 4-chain local argmax (strict > keeps lowest index per chain)
            float bv0 = -INFINITY, bv1 = -INFINITY, bv2 = -INFINITY, bv3 = -INFINITY;
            int bi0 = 0, bi1 = 0, bi2 = 0, bi3 = 0;
#pragma unroll
            for (int j = 0; j < 8; j++) {
                int nb = 4 * (j * 512 + tid);
#pragma unroll
                for (int t = 0; t < 4; t++) {
                    int r = j * 4 + t;
                    float dx = __fsub_rn(x[r], cx);
                    float dy = __fsub_rn(y[r], cy);
                    float dz = __fsub_rn(z[r], cz);
                    float d = sq3(dx, dy, dz);
                    float dj = fminf(dist[r], d);
                    dist[r] = dj;
                    int n = nb + t;
                    switch (t) {
                        case 0: if (dj > bv0) { bv0 = dj; bi0 = n; } break;
                        case 1: if (dj > bv1) { bv1 = dj; bi1 = n; } break;
                        case 2: if (dj > bv2) { bv2 = dj; bi2 = n; } break;
                        case 3: if (dj > bv3) { bv3 = dj; bi3 = n; } break;
                    }
                }
            }
            float fv = bv0; int fi = bi0;
            if (bv1 > fv || (bv1 == fv && bi1 < fi)) { fv = bv1; fi = bi1; }
            if (bv2 > fv || (bv2 == fv && bi2 < fi)) { fv = bv2; fi = bi2; }
            if (bv3 > fv || (bv3 == fv && bi3 < fi)) { fv = bv3; fi = bi3; }
            // wave (64-lane) argmax reduce, lower index wins ties
#pragma unroll
            for (int off = 32; off >= 1; off >>= 1) {
                float ov = __shfl_down(fv, off);
                int oi = __shfl_down(fi, off);
                if (ov > fv || (ov == fv && oi < fi)) { fv = ov; fi = oi; }
            }
            // dist >= 0 so float bits are order-monotone; ~idx -> lowest index wins max
            if ((tid & 63) == 0) {
                unsigned long long packed =
                    ((unsigned long long)__float_as_uint(fv) << 32) |
                    (unsigned)(0xFFFFFFFFu - (unsigned)fi);
                atomicMax(&sh.f.slot[it], packed);
            }
            __syncthreads();  // the only barrier per iteration
            unsigned long long w = sh.f.slot[it];
            int idx = (int)(0xFFFFFFFFu - (unsigned)w);
            const float* wp = p + (size_t)idx * 3;  // broadcast same-address load, L2-hit
            cx = wp[0]; cy = wp[1]; cz = wp[2];
        }
        if (tid == 0) {
            asm volatile("s_waitcnt vmcnt(0)" ::: "memory");
            __hip_atomic_store(&prog[b], (unsigned)GG, __ATOMIC_RELAXED,
                               __HIP_MEMORY_SCOPE_AGENT);
        }
        return;
    }

    // ================= group path: two (b,g) per block =================
    const int h = tid & 255;     // index within half
    const int half = tid >> 8;   // 0 or 1
    const int lane = h & 63, wid = h >> 6;

    // g-ascending, XCD-swizzled mapping. bid' = r*8+x; g = r>>1; pairSel = r&1.
    // XCD x serves batches 4x..4x+3 -> points stay L2-resident per XCD.
    int bid = blockIdx.x - BB;
    int x = bid & 7;
    int r = bid >> 3;  // 0..255
    int g = r >> 1;
    int pairSel = r & 1;
    int b = x * 4 + pairSel * 2 + half;

    const float* p = pts + (size_t)b * NN * 3;
    const float4* p4 = (const float4*)p;

    // cooperative init (before the spin so non-polling lanes' work is done)
    for (int i = tid; i < 3 * HH; i += 512) sh.g.w1s[i] = w1[i];
    if (tid < HH) sh.g.b1s[tid] = b1[tid];
    for (int i = h; i < NBUCK; i += 256) sh.g.u.hist[half][i] = 0;
    if (h == 0) sh.g.cntS[half] = 0;
    if (tid == 0) sh.g.fbS = 0;

    // wait for our centroid: relaxed sc1 poll (no cache invalidation), then sc1 data loads
    if (h == 0) {
        unsigned need = (unsigned)(g + 1);
        while (__hip_atomic_load(&prog[b], __ATOMIC_RELAXED,
                                 __HIP_MEMORY_SCOPE_AGENT) < need)
            __builtin_amdgcn_s_sleep(32);
        asm volatile("" ::: "memory");  // no hoisting of the data loads above the poll
        const unsigned long long* cp =
            (const unsigned long long*)&cent_pad[(size_t)b * GG + g];
        unsigned long long lo =
            __hip_atomic_load(cp, __ATOMIC_RELAXED, __HIP_MEMORY_SCOPE_AGENT);
        unsigned long long hi =
            __hip_atomic_load(cp + 1, __ATOMIC_RELAXED, __HIP_MEMORY_SCOPE_AGENT);
        sh.g.c4s[half] = make_float4(
            __uint_as_float((unsigned)lo), __uint_as_float((unsigned)(lo >> 32)),
            __uint_as_float((unsigned)hi), __uint_as_float((unsigned)(hi >> 32)));
    }
    __syncthreads();
    float4 c4 = sh.g.c4s[half];

    // ---- pass 1: histogram of 11-bit key prefixes
    for (int i = 0; i < 16; i++) {
        int t4 = i * 256 + h;
        float4 A = p4[3 * t4], B = p4[3 * t4 + 1], C = p4[3 * t4 + 2];
        unsigned k0 = distkey(A.x, A.y, A.z, c4);
        unsigned k1 = distkey(A.w, B.x, B.y, c4);
        unsigned k2 = distkey(B.z, B.w, C.x, c4);
        unsigned k3 = distkey(C.y, C.z, C.w, c4);
        atomicAdd(&sh.g.u.hist[half][k0 >> 21], 1u);
        atomicAdd(&sh.g.u.hist[half][k1 >> 21], 1u);
        atomicAdd(&sh.g.u.hist[half][k2 >> 21], 1u);
        atomicAdd(&sh.g.u.hist[half][k3 >> 21], 1u);
    }
    __syncthreads();

    // ---- boundary bucket: smallest T with cumcount(<=T) >= 64
    {
        uint4 h0 = ((const uint4*)sh.g.u.hist[half])[h * 2];
        uint4 h1 = ((const uint4*)sh.g.u.hist[half])[h * 2 + 1];
        int loc[8] = {(int)h0.x, (int)h0.y, (int)h0.z, (int)h0.w,
                      (int)h1.x, (int)h1.y, (int)h1.z, (int)h1.w};
        int s = 0;
#pragma unroll
        for (int j = 0; j < 8; j++) s += loc[j];
        int v = s;
#pragma unroll
        for (int off = 1; off < 64; off <<= 1) {
            int o = __shfl_up(v, off);
            if (lane >= off) v += o;
        }
        if (lane == 63) sh.g.waveSum[half][wid] = v;
        __syncthreads();
        int base = 0;
        for (int w = 0; w < wid; w++) base += sh.g.waveSum[half][w];
        int c = base + v - s;  // exclusive prefix at this thread's first bucket
#pragma unroll
        for (int j = 0; j < 8; j++) {
            if (c < KK && c + loc[j] >= KK) sh.g.TA_S[half] = (unsigned)(h * 8 + j);
            c += loc[j];
        }
        __syncthreads();
    }
    unsigned TA = sh.g.TA_S[half];

    // ---- pass 2: recompute keys, collect candidates in buckets <= TA
    for (int i = 0; i < 16; i++) {
        int t4 = i * 256 + h;
        float4 A = p4[3 * t4], B = p4[3 * t4 + 1], C = p4[3 * t4 + 2];
        unsigned k[4];
        k[0] = distkey(A.x, A.y, A.z, c4);
        k[1] = distkey(A.w, B.x, B.y, c4);
        k[2] = distkey(B.z, B.w, C.x, c4);
        k[3] = distkey(C.y, C.z, C.w, c4);
#pragma unroll
        for (int q = 0; q < 4; q++) {
            if ((k[q] >> 21) <= TA) {
                int pos = atomicAdd(&sh.g.cntS[half], 1);
                if (pos < CANDCAP)
                    sh.g.u.cand[half][pos] =
                        ((unsigned long long)k[q] << 32) | (unsigned)(4 * t4 + q);
            }
        }
    }
    __syncthreads();
    int cnt = sh.g.cntS[half];  // >= 64 by construction
    if (h == 0 && cnt > CANDCAP) sh.g.fbS = 1;  // shared so both halves branch together
    __syncthreads();
    int fb = sh.g.fbS;

    if (!fb) {
        // ---- exact rank-select of the 64 lexicographically smallest (key,idx)
        for (int c0 = h; c0 < cnt; c0 += 256) {
            unsigned long long pr = sh.g.u.cand[half][c0];
            int rank = 0;
            for (int j = 0; j < cnt; j++) rank += (sh.g.u.cand[half][j] < pr);
            if (rank < KK) sh.g.selIdx[half][rank] = (int)(unsigned)pr;
        }
        __syncthreads();
    } else {
        // ---- pathological fallback (never triggers on real data): exact 64-round
        // min-extraction, keys recomputed each round; same barrier count in both halves
        if (h == 0) sh.g.lastS[half] = 0ull;
        __syncthreads();
        for (int rr = 0; rr < KK; rr++) {
            unsigned long long last = sh.g.lastS[half];
            unsigned long long best = 0xFFFFFFFFFFFFFFFFull;
            for (int i = 0; i < 16; i++) {
                int t4 = i * 256 + h;
                float4 A = p4[3 * t4], B = p4[3 * t4 + 1], C = p4[3 * t4 + 2];
                unsigned k[4];
                k[0] = distkey(A.x, A.y, A.z, c4);
                k[1] = distkey(A.w, B.x, B.y, c4);
                k[2] = distkey(B.z, B.w, C.x, c4);
                k[3] = distkey(C.y, C.z, C.w, c4);
#pragma unroll
                for (int q = 0; q < 4; q++) {
                    unsigned long long pr =
                        ((unsigned long long)k[q] << 32) | (unsigned)(4 * t4 + q);
                    if ((rr == 0 || pr > last) && pr < best) best = pr;
                }
            }
            unsigned blo = (unsigned)best, bhi = (unsigned)(best >> 32);
#pragma unroll
            for (int off = 32; off >= 1; off >>= 1) {
                unsigned olo = __shfl_down(blo, off);
                unsigned ohi = __shfl_down(bhi, off);
                unsigned long long ob = ((unsigned long long)ohi << 32) | olo;
                unsigned long long cur = ((unsigned long long)bhi << 32) | blo;
                if (ob < cur) { blo = olo; bhi = ohi; }
            }
            if (lane == 0) sh.g.wmin[half][wid] = ((unsigned long long)bhi << 32) | blo;
            __syncthreads();
            if (h == 0) {
                unsigned long long m = sh.g.wmin[half][0];
                for (int w = 1; w < 4; w++)
                    if (sh.g.wmin[half][w] < m) m = sh.g.wmin[half][w];
                sh.g.selIdx[half][rr] = (int)(unsigned)m;
                sh.g.lastS[half] = m;
            }
            __syncthreads();
        }
    }

    // ---- gather + local coords
    if (h < KK) {
        int n = sh.g.selIdx[half][h];
        float px = p[n * 3], py = p[n * 3 + 1], pz = p[n * 3 + 2];
        sh.g.localPt[half][h] = make_float4(px - c4.x, py - c4.y, pz - c4.z, 0.f);
    }
    __syncthreads();
    // ---- layer1 + exact GELU + mean over K (2 threads per feature, 32 pts each)
    {
        int f = h & 127, halfk = h >> 7;
        float wa = sh.g.w1s[f], wb = sh.g.w1s[HH + f], wc = sh.g.w1s[2 * HH + f];
        float bb = sh.g.b1s[f];
        float s = 0.f;
        for (int k = halfk * 32; k < halfk * 32 + 32; k++) {
            float4 lp = sh.g.localPt[half][k];
            float a = lp.x * wa + lp.y * wb + lp.z * wc + bb;
            float hh = 0.5f * a * (1.0f + erff(a * 0.70710678118654752440f));
            s += hh;
        }
        sh.g.partial[half][h] = s;
    }
    __syncthreads();
    if (h < HH)
        sh.g.hbar[half][h] =
            (sh.g.partial[half][h] + sh.g.partial[half][h + HH]) * (1.0f / 64.0f);
    __syncthreads();
    // ---- layer2: tokens = hbar @ w2 + b2   (mean commutes with the linear layer)
    for (int f2 = h; f2 < DD; f2 += 256) {
        const float4* wrow = (const float4*)(w2t + f2 * HH);
        const float4* hb = (const float4*)sh.g.hbar[half];
        float acc = b2[f2];
#pragma unroll 8
        for (int q = 0; q < 32; q++) {
            float4 w4 = wrow[q];
            float4 h4 = hb[q];
            acc += h4.x * w4.x + h4.y * w4.y + h4.z * w4.z + h4.w * w4.w;
        }
        sh.g.toks[half][f2] = acc;
    }
    __syncthreads();
    // ---- LayerNorm over 384
    {
        float s1 = 0.f, s2 = 0.f;
        for (int f2 = h; f2 < DD; f2 += 256) {
            float v = sh.g.toks[half][f2];
            s1 += v;
            s2 += v * v;
        }
#pragma unroll
        for (int off = 32; off >= 1; off >>= 1) {
            s1 += __shfl_down(s1, off);
            s2 += __shfl_down(s2, off);
        }
        if (lane == 0) { sh.g.partial[half][wid] = s1; sh.g.red2[half][wid] = s2; }
        __syncthreads();
        if (h == 0) {
            float t1 = sh.g.partial[half][0] + sh.g.partial[half][1] +
                       sh.g.partial[half][2] + sh.g.partial[half][3];
            float t2 = sh.g.red2[half][0] + sh.g.red2[half][1] + sh.g.red2[half][2] +
                       sh.g.red2[half][3];
            float mu = t1 / (float)DD;
            float var = t2 / (float)DD - mu * mu;
            sh.g.muS[half] = mu;
            sh.g.rstdS[half] = rsqrtf(var + LN_EPS);
        }
        __syncthreads();
    }
    float mu = sh.g.muS[half], rstd = sh.g.rstdS[half];
    float* outp = tok_out + ((size_t)b * GG + g) * DD;
    for (int f2 = h; f2 < DD; f2 += 256) {
        outp[f2] = (sh.g.toks[half][f2] - mu) * rstd * lns[f2] + lnb[f2];
    }
}

extern "C" void kernel_launch(void* const* d_in, const int* in_sizes, int n_in,
                              void* d_out, int out_size, void* d_ws, size_t ws_size,
                              hipStream_t stream) {
    const float* pts = (const float*)d_in[0];
    const float* w1 = (const float*)d_in[1];
    const float* b1 = (const float*)d_in[2];
    const float* w2 = (const float*)d_in[3];
    const float* b2 = (const float*)d_in[4];
    const float* lns = (const float*)d_in[5];
    const float* lnb = (const float*)d_in[6];
    float* out = (float*)d_out;

    // ws layout: cent_pad [B*G float4] @0 (64KB), w2t [384*128 f32] @64KB (192KB),
    //            prog [B u32] @256KB
    float4* cent_pad = (float4*)d_ws;
    float* w2t = (float*)((char*)d_ws + 64 * 1024);
    unsigned* prog = (unsigned*)((char*)d_ws + 256 * 1024);

    prep_kernel<<<192, 256, 0, stream>>>(w2, w2t, prog);
    // 32 fps blocks first (scheduled first, co-resident), then 2048 two-group blocks
    fused_kernel<<<BB + (BB * GG) / 2, 512, 0, stream>>>(
        pts, w1, b1, w2t, b2, lns, lnb, out, cent_pad, out + BB * GG * 3, prog);
}

// Round 3
// 665.020 us; speedup vs baseline: 2.5816x; 2.5816x over previous
//
#include <hip/hip_runtime.h>
#include <math.h>

#define BB 32
#define NN 16384
#define GG 128
#define KK 64
#define HH 128
#define DD 384
#define LN_EPS 1e-5f
#define NBUCK 2048
#define CANDCAP 1024

// round-to-nearest sum of 3 squares, matching jnp.sum(x**2, -1) order, no FMA contraction
__device__ __forceinline__ float sq3(float x, float y, float z) {
    return __fadd_rn(__fadd_rn(__fmul_rn(x, x), __fmul_rn(y, y)), __fmul_rn(z, z));
}

// order-preserving uint key of dist2, same formula/rounding as reference
__device__ __forceinline__ unsigned distkey(float px, float py, float pz, float4 c4) {
    float p2 = sq3(px, py, pz);
    float dot = __fadd_rn(__fadd_rn(__fmul_rn(c4.x, px), __fmul_rn(c4.y, py)),
                          __fmul_rn(c4.z, pz));
    float d = __fsub_rn(__fadd_rn(c4.w, p2), __fmul_rn(2.0f, dot));
    unsigned u = __float_as_uint(d);
    return u ^ ((u & 0x80000000u) ? 0xFFFFFFFFu : 0x80000000u);
}

// ---------------- prep: transpose w2 [128,384] -> w2t [384,128] ----------------
__global__ void prep_kernel(const float* __restrict__ w2, float* __restrict__ w2t) {
    int i = blockIdx.x * 256 + threadIdx.x;  // over DD*HH = 49152
    if (i < HH * DD) {
        int f = i >> 7;    // 0..383
        int k = i & 127;   // 0..127
        w2t[i] = w2[k * DD + f];
    }
}

// ---------------- FPS: one block per batch, 1024 threads, 16 pts/thread ------------
// The full working set (x,y,z,dist = 64 floats/thread ~ 95 VGPR) fits in registers
// under __launch_bounds__(1024,4) (4 waves/SIMD, 128-VGPR budget) -> NO memory traffic
// in the distance loop (round-0's 512-thr version had 2 waves/SIMD and re-read xyz
// from L1/L2 every iteration: 2.16us/iter vs ~0.65us VALU floor).
// Per-iteration tail: per-wave winners (key + coords) go to LDS; every thread scans the
// 16 entries -> next centroid comes from LDS, no dependent global load.
__global__ __launch_bounds__(1024, 4) void fps_kernel(const float* __restrict__ pts,
                                                      float* __restrict__ cent_out,
                                                      float4* __restrict__ cent_pad) {
    const int b = blockIdx.x;
    const int tid = threadIdx.x;
    const float* p = pts + (size_t)b * NN * 3;
    const float4* p4 = (const float4*)p;

    // thread owns quads q = j*1024+tid (j=0..3): points 4q..4q+3, loaded as 3 float4
    float x[16], y[16], z[16], dist[16];
#pragma unroll
    for (int j = 0; j < 4; j++) {
        int q = j * 1024 + tid;
        float4 A = p4[3 * q], B = p4[3 * q + 1], C = p4[3 * q + 2];
        x[j * 4 + 0] = A.x; y[j * 4 + 0] = A.y; z[j * 4 + 0] = A.z;
        x[j * 4 + 1] = A.w; y[j * 4 + 1] = B.x; z[j * 4 + 1] = B.y;
        x[j * 4 + 2] = B.z; y[j * 4 + 2] = B.w; z[j * 4 + 2] = C.x;
        x[j * 4 + 3] = C.y; y[j * 4 + 3] = C.z; z[j * 4 + 3] = C.w;
#pragma unroll
        for (int t = 0; t < 4; t++) dist[j * 4 + t] = INFINITY;
    }

    __shared__ unsigned long long wkey[16];  // per-wave winner key
    __shared__ float wx[16], wy[16], wz[16]; // per-wave winner coords

    float cx = p[0], cy = p[1], cz = p[2];  // deterministic start at index 0
    const int wid = tid >> 6;

    for (int it = 0; it < GG; it++) {
        if (tid == 0) {
            float* co = cent_out + ((size_t)b * GG + it) * 3;
            co[0] = cx; co[1] = cy; co[2] = cz;
            cent_pad[b * GG + it] = make_float4(cx, cy, cz, sq3(cx, cy, cz));
        }
        if (it == GG - 1) break;  // last argmax unused

        // distance update + 4-chain local argmax (strict > keeps lowest index per chain)
        float bv0 = -INFINITY, bv1 = -INFINITY, bv2 = -INFINITY, bv3 = -INFINITY;
        int bi0 = 0, bi1 = 0, bi2 = 0, bi3 = 0;
#pragma unroll
        for (int j = 0; j < 4; j++) {
            int nb = 4 * (j * 1024 + tid);
#pragma unroll
            for (int t = 0; t < 4; t++) {
                int r = j * 4 + t;
                float dx = __fsub_rn(x[r], cx);
                float dy = __fsub_rn(y[r], cy);
                float dz = __fsub_rn(z[r], cz);
                float d = sq3(dx, dy, dz);
                float dj = fminf(dist[r], d);
                dist[r] = dj;
                int n = nb + t;
                switch (t) {
                    case 0: if (dj > bv0) { bv0 = dj; bi0 = n; } break;
                    case 1: if (dj > bv1) { bv1 = dj; bi1 = n; } break;
                    case 2: if (dj > bv2) { bv2 = dj; bi2 = n; } break;
                    case 3: if (dj > bv3) { bv3 = dj; bi3 = n; } break;
                }
            }
        }
        // merge chains, lowest index wins ties
        float mfv = bv0; int mfi = bi0;
        if (bv1 > mfv || (bv1 == mfv && bi1 < mfi)) { mfv = bv1; mfi = bi1; }
        if (bv2 > mfv || (bv2 == mfv && bi2 < mfi)) { mfv = bv2; mfi = bi2; }
        if (bv3 > mfv || (bv3 == mfv && bi3 < mfi)) { mfv = bv3; mfi = bi3; }

        // wave (64-lane) argmax reduce, lower index wins ties
        float fv = mfv; int fi = mfi;
#pragma unroll
        for (int off = 32; off >= 1; off >>= 1) {
            float ov = __shfl_down(fv, off);
            int oi = __shfl_down(fi, off);
            if (ov > fv || (ov == fv && oi < fi)) { fv = ov; fi = oi; }
        }
        int wfi = __shfl(fi, 0);  // broadcast wave winner index
        // exactly one lane owns point wfi: it recovers coords (constant indices only)
        if (mfi == wfi) {
            int jj = (wfi >> 2) - tid;  // = j*1024
            int tt = wfi & 3;
            float sx = 0.f, sy = 0.f, sz = 0.f;
#pragma unroll
            for (int j = 0; j < 4; j++) {
                if (jj == j * 1024) {
#pragma unroll
                    for (int t = 0; t < 4; t++) {
                        if (tt == t) { sx = x[j * 4 + t]; sy = y[j * 4 + t]; sz = z[j * 4 + t]; }
                    }
                }
            }
            // dist >= 0 so float bits are order-monotone; ~idx -> lowest index wins max
            wkey[wid] = ((unsigned long long)__float_as_uint(mfv) << 32) |
                        (unsigned)(0xFFFFFFFFu - (unsigned)mfi);
            wx[wid] = sx; wy[wid] = sy; wz[wid] = sz;
        }
        __syncthreads();  // B1: all 16 wave winners visible
        // every thread scans the 16 entries (broadcast LDS reads, conflict-free)
        unsigned long long bk = wkey[0];
        int bw = 0;
#pragma unroll
        for (int w = 1; w < 16; w++) {
            unsigned long long k2 = wkey[w];
            if (k2 > bk) { bk = k2; bw = w; }
        }
        cx = wx[bw]; cy = wy[bw]; cz = wz[bw];
        __syncthreads();  // B2: scans done before next iteration overwrites wkey/wx/y/z
    }
}

// ---------------- group kernel: dist2 + exact top-64 + MLP + mean + LN ----------------
// Keys are recomputed instead of cached (key[64] live across barriers spilled to
// scratch at VGPR=76). hist/cand overlay saves 8KB LDS.
__global__ __launch_bounds__(256, 6) void group_kernel(
    const float* __restrict__ pts, const float4* __restrict__ cent_pad,
    const float* __restrict__ w1, const float* __restrict__ b1,
    const float* __restrict__ w2t, const float* __restrict__ b2,
    const float* __restrict__ lns, const float* __restrict__ lnb,
    float* __restrict__ tok_out) {
    __shared__ __align__(16) union {
        unsigned hist[NBUCK];              // phase 1-2
        unsigned long long cand[CANDCAP];  // phase 3+ (hist dead after scan)
    } sh;
    __shared__ int selIdx[KK];
    __shared__ float4 localPt[KK];
    __shared__ float w1s[3 * HH];
    __shared__ float b1s[HH];
    __shared__ __align__(16) float hbar[HH];
    __shared__ float partial[256];
    __shared__ float red2[8];
    __shared__ float toks[DD];
    __shared__ int waveSum[4];
    __shared__ unsigned long long wmin[4];
    __shared__ unsigned TA_S;
    __shared__ int cntS;
    __shared__ unsigned long long lastS;
    __shared__ float muS, rstdS;

    const int tid = threadIdx.x;
    // XCD-aware swizzle: each XCD sees only 4 batches' points (768KB -> L2 resident)
    int bid = blockIdx.x;
    int xcd = bid & 7, sub = bid >> 3;
    int b = xcd * 4 + (sub >> 7);
    int g = sub & 127;

    const float* p = pts + (size_t)b * NN * 3;
    const float4* p4 = (const float4*)p;
    float4 c4 = cent_pad[b * GG + g];

    for (int i = tid; i < 3 * HH; i += 256) w1s[i] = w1[i];
    if (tid < HH) b1s[tid] = b1[tid];
    for (int i = tid; i < NBUCK; i += 256) sh.hist[i] = 0;
    if (tid == 0) cntS = 0;
    __syncthreads();

    // ---- pass 1: histogram of 11-bit key prefixes (keys recomputed later, not stored)
    for (int i = 0; i < 16; i++) {
        int t4 = i * 256 + tid;  // quad id; points 4*t4 .. 4*t4+3
        float4 A = p4[3 * t4], B = p4[3 * t4 + 1], C = p4[3 * t4 + 2];
        unsigned k0 = distkey(A.x, A.y, A.z, c4);
        unsigned k1 = distkey(A.w, B.x, B.y, c4);
        unsigned k2 = distkey(B.z, B.w, C.x, c4);
        unsigned k3 = distkey(C.y, C.z, C.w, c4);
        atomicAdd(&sh.hist[k0 >> 21], 1u);
        atomicAdd(&sh.hist[k1 >> 21], 1u);
        atomicAdd(&sh.hist[k2 >> 21], 1u);
        atomicAdd(&sh.hist[k3 >> 21], 1u);
    }
    __syncthreads();

    // ---- find boundary bucket: smallest T with cumcount(<=T) >= 64
    {
        uint4 h0 = ((const uint4*)sh.hist)[tid * 2];
        uint4 h1 = ((const uint4*)sh.hist)[tid * 2 + 1];
        int loc[8] = {(int)h0.x, (int)h0.y, (int)h0.z, (int)h0.w,
                      (int)h1.x, (int)h1.y, (int)h1.z, (int)h1.w};
        int s = 0;
#pragma unroll
        for (int j = 0; j < 8; j++) s += loc[j];
        int lane = tid & 63, wid = tid >> 6;
        int v = s;
#pragma unroll
        for (int off = 1; off < 64; off <<= 1) {
            int o = __shfl_up(v, off);
            if (lane >= off) v += o;
        }
        if (lane == 63) waveSum[wid] = v;
        __syncthreads();
        int base = 0;
        for (int w = 0; w < wid; w++) base += waveSum[w];
        int c = base + v - s;  // exclusive prefix at this thread's first bucket
#pragma unroll
        for (int j = 0; j < 8; j++) {
            if (c < KK && c + loc[j] >= KK) TA_S = (unsigned)(tid * 8 + j);
            c += loc[j];
        }
        __syncthreads();
    }
    unsigned TA = TA_S;

    // ---- pass 2: recompute keys, collect candidates in buckets <= TA (~330 expected)
    for (int i = 0; i < 16; i++) {
        int t4 = i * 256 + tid;
        float4 A = p4[3 * t4], B = p4[3 * t4 + 1], C = p4[3 * t4 + 2];
        unsigned k[4];
        k[0] = distkey(A.x, A.y, A.z, c4);
        k[1] = distkey(A.w, B.x, B.y, c4);
        k[2] = distkey(B.z, B.w, C.x, c4);
        k[3] = distkey(C.y, C.z, C.w, c4);
#pragma unroll
        for (int q = 0; q < 4; q++) {
            if ((k[q] >> 21) <= TA) {
                int pos = atomicAdd(&cntS, 1);
                if (pos < CANDCAP)
                    sh.cand[pos] =
                        ((unsigned long long)k[q] << 32) | (unsigned)(4 * t4 + q);
            }
        }
    }
    __syncthreads();
    int cnt = cntS;  // >= 64 by construction

    if (cnt <= CANDCAP) {
        // ---- exact rank-select of the 64 lexicographically smallest (key,idx)
        for (int c0 = tid; c0 < cnt; c0 += 256) {
            unsigned long long pr = sh.cand[c0];
            int rank = 0;
            for (int j = 0; j < cnt; j++) rank += (sh.cand[j] < pr);
            if (rank < KK) selIdx[rank] = (int)(unsigned)pr;
        }
        __syncthreads();
    } else {
        // ---- pathological fallback (never triggers on real data): exact 64-round
        // min-extraction, keys recomputed each round
        if (tid == 0) lastS = 0ull;
        __syncthreads();
        for (int r = 0; r < KK; r++) {
            unsigned long long last = lastS;
            unsigned long long best = 0xFFFFFFFFFFFFFFFFull;
            for (int i = 0; i < 16; i++) {
                int t4 = i * 256 + tid;
                float4 A = p4[3 * t4], B = p4[3 * t4 + 1], C = p4[3 * t4 + 2];
                unsigned k[4];
                k[0] = distkey(A.x, A.y, A.z, c4);
                k[1] = distkey(A.w, B.x, B.y, c4);
                k[2] = distkey(B.z, B.w, C.x, c4);
                k[3] = distkey(C.y, C.z, C.w, c4);
#pragma unroll
                for (int q = 0; q < 4; q++) {
                    unsigned long long pr =
                        ((unsigned long long)k[q] << 32) | (unsigned)(4 * t4 + q);
                    if ((r == 0 || pr > last) && pr < best) best = pr;
                }
            }
            unsigned blo = (unsigned)best, bhi = (unsigned)(best >> 32);
#pragma unroll
            for (int off = 32; off >= 1; off >>= 1) {
                unsigned olo = __shfl_down(blo, off);
                unsigned ohi = __shfl_down(bhi, off);
                unsigned long long ob = ((unsigned long long)ohi << 32) | olo;
                unsigned long long cur = ((unsigned long long)bhi << 32) | blo;
                if (ob < cur) { blo = olo; bhi = ohi; }
            }
            int lane = tid & 63, wid = tid >> 6;
            if (lane == 0) wmin[wid] = ((unsigned long long)bhi << 32) | blo;
            __syncthreads();
            if (tid == 0) {
                unsigned long long m = wmin[0];
                for (int w = 1; w < 4; w++) if (wmin[w] < m) m = wmin[w];
                selIdx[r] = (int)(unsigned)m;
                lastS = m;
            }
            __syncthreads();
        }
    }

    // ---- gather + local coords
    if (tid < KK) {
        int n = selIdx[tid];
        float px = p[n * 3], py = p[n * 3 + 1], pz = p[n * 3 + 2];
        localPt[tid] = make_float4(px - c4.x, py - c4.y, pz - c4.z, 0.f);
    }
    __syncthreads();
    // ---- layer1 + exact GELU + mean over K (2 threads per feature, 32 pts each)
    {
        int f = tid & 127, half = tid >> 7;
        float wa = w1s[f], wb = w1s[HH + f], wc = w1s[2 * HH + f], bb = b1s[f];
        float s = 0.f;
        for (int k = half * 32; k < half * 32 + 32; k++) {
            float4 lp = localPt[k];
            float a = lp.x * wa + lp.y * wb + lp.z * wc + bb;
            float hh = 0.5f * a * (1.0f + erff(a * 0.70710678118654752440f));
            s += hh;
        }
        partial[tid] = s;
    }
    __syncthreads();
    if (tid < HH) hbar[tid] = (partial[tid] + partial[tid + HH]) * (1.0f / 64.0f);
    __syncthreads();
    // ---- layer2: tokens = hbar @ w2 + b2   (mean commutes with the linear layer)
    for (int f2 = tid; f2 < DD; f2 += 256) {
        const float4* wrow = (const float4*)(w2t + f2 * HH);
        const float4* hb = (const float4*)hbar;
        float acc = b2[f2];
#pragma unroll 8
        for (int q = 0; q < 32; q++) {
            float4 w4 = wrow[q];
            float4 h4 = hb[q];
            acc += h4.x * w4.x + h4.y * w4.y + h4.z * w4.z + h4.w * w4.w;
        }
        toks[f2] = acc;
    }
    __syncthreads();
    // ---- LayerNorm over 384
    {
        float s1 = 0.f, s2 = 0.f;
        for (int f2 = tid; f2 < DD; f2 += 256) {
            float v = toks[f2];
            s1 += v;
            s2 += v * v;
        }
#pragma unroll
        for (int off = 32; off >= 1; off >>= 1) {
            s1 += __shfl_down(s1, off);
            s2 += __shfl_down(s2, off);
        }
        int lane = tid & 63, wid = tid >> 6;
        if (lane == 0) { partial[wid] = s1; red2[wid] = s2; }
        __syncthreads();
        if (tid == 0) {
            float t1 = partial[0] + partial[1] + partial[2] + partial[3];
            float t2 = red2[0] + red2[1] + red2[2] + red2[3];
            float mu = t1 / (float)DD;
            float var = t2 / (float)DD - mu * mu;
            muS = mu;
            rstdS = rsqrtf(var + LN_EPS);
        }
        __syncthreads();
    }
    float mu = muS, rstd = rstdS;
    float* outp = tok_out + ((size_t)b * GG + g) * DD;
    for (int f2 = tid; f2 < DD; f2 += 256) {
        outp[f2] = (toks[f2] - mu) * rstd * lns[f2] + lnb[f2];
    }
}

extern "C" void kernel_launch(void* const* d_in, const int* in_sizes, int n_in,
                              void* d_out, int out_size, void* d_ws, size_t ws_size,
                              hipStream_t stream) {
    const float* pts = (const float*)d_in[0];
    const float* w1 = (const float*)d_in[1];
    const float* b1 = (const float*)d_in[2];
    const float* w2 = (const float*)d_in[3];
    const float* b2 = (const float*)d_in[4];
    const float* lns = (const float*)d_in[5];
    const float* lnb = (const float*)d_in[6];
    float* out = (float*)d_out;

    // ws layout: cent_pad [B*G float4] = 64KB, then w2t [384*128 floats] = 192KB
    float4* cent_pad = (float4*)d_ws;
    float* w2t = (float*)((char*)d_ws + BB * GG * sizeof(float4));

    prep_kernel<<<192, 256, 0, stream>>>(w2, w2t);
    fps_kernel<<<BB, 1024, 0, stream>>>(pts, out, cent_pad);
    group_kernel<<<BB * GG, 256, 0, stream>>>(pts, cent_pad, w1, b1, w2t, b2, lns, lnb,
                                              out + BB * GG * 3);
}

// Round 5
// 595.564 us; speedup vs baseline: 2.8827x; 1.1166x over previous
//
#include <hip/hip_runtime.h>
#include <math.h>

#define BB 32
#define NN 16384
#define GG 128
#define KK 64
#define HH 128
#define DD 384
#define LN_EPS 1e-5f
#define NBUCK 2048
#define CANDCAP 1024

// round-to-nearest sum of 3 squares, matching jnp.sum(x**2, -1) order, no FMA contraction
__device__ __forceinline__ float sq3(float x, float y, float z) {
    return __fadd_rn(__fadd_rn(__fmul_rn(x, x), __fmul_rn(y, y)), __fmul_rn(z, z));
}

// order-preserving uint key of dist2, same formula/rounding as reference
__device__ __forceinline__ unsigned distkey(float px, float py, float pz, float4 c4) {
    float p2 = sq3(px, py, pz);
    float dot = __fadd_rn(__fadd_rn(__fmul_rn(c4.x, px), __fmul_rn(c4.y, py)),
                          __fmul_rn(c4.z, pz));
    float d = __fsub_rn(__fadd_rn(c4.w, p2), __fmul_rn(2.0f, dot));
    unsigned u = __float_as_uint(d);
    return u ^ ((u & 0x80000000u) ? 0xFFFFFFFFu : 0x80000000u);
}

// ---------------- prep: transpose w2 [128,384] -> w2t [384,128] ----------------
__global__ void prep_kernel(const float* __restrict__ w2, float* __restrict__ w2t) {
    int i = blockIdx.x * 256 + threadIdx.x;  // over DD*HH = 49152
    if (i < HH * DD) {
        int f = i >> 7;    // 0..383
        int k = i & 127;   // 0..127
        w2t[i] = w2[k * DD + f];
    }
}

// ---------------- FPS: one block per batch, 512 threads, 32 pts/thread ----------------
// amdgpu_waves_per_eu(2,2): occupancy PINNED at 2 waves/SIMD (we launch 1 block/CU, so
// higher occupancy is unreachable anyway) -> VGPR budget 256/lane. The full working set
// (x,y,z,dist = 128 floats + ~40 scalars ~ 170 VGPR) stays in registers: ZERO memory
// traffic in the distance loop. Round 0 (VGPR=84) spilled ~60 floats/thread and
// re-filled them every iteration -- the 39% VALU-idle gap vs the ~0.65us/iter floor.
// Round 3 (launch_bounds(1024,4), VGPR=64) was the same allocator failure: min-occupancy
// hints don't stop the allocator from squeezing for MORE occupancy; the (2,2) MAX does.
// Tail: per-wave winner lane deposits (key,x,y,z) in LDS; everyone scans 8 entries.
// Ping-pong parity -> ONE barrier per iteration, no dependent global winner load.
__global__ __launch_bounds__(512) void __attribute__((amdgpu_waves_per_eu(2, 2)))
fps_kernel(const float* __restrict__ pts, float* __restrict__ cent_out,
           float4* __restrict__ cent_pad) {
    const int b = blockIdx.x;
    const int tid = threadIdx.x;
    const float* p = pts + (size_t)b * NN * 3;
    const float4* p4 = (const float4*)p;

    // thread owns quads q = j*512+tid (j=0..7): points 4q..4q+3, loaded as 3 float4
    float x[32], y[32], z[32], dist[32];
#pragma unroll
    for (int j = 0; j < 8; j++) {
        int q = j * 512 + tid;
        float4 A = p4[3 * q], B = p4[3 * q + 1], C = p4[3 * q + 2];
        x[j * 4 + 0] = A.x; y[j * 4 + 0] = A.y; z[j * 4 + 0] = A.z;
        x[j * 4 + 1] = A.w; y[j * 4 + 1] = B.x; z[j * 4 + 1] = B.y;
        x[j * 4 + 2] = B.z; y[j * 4 + 2] = B.w; z[j * 4 + 2] = C.x;
        x[j * 4 + 3] = C.y; y[j * 4 + 3] = C.z; z[j * 4 + 3] = C.w;
#pragma unroll
        for (int t = 0; t < 4; t++) dist[j * 4 + t] = INFINITY;
    }

    __shared__ unsigned long long wkey[2][8];  // per-wave winner key, ping-pong parity
    __shared__ float wx[2][8], wy[2][8], wz[2][8];

    float cx = p[0], cy = p[1], cz = p[2];  // deterministic start at index 0
    const int wid = tid >> 6;

    for (int it = 0; it < GG; it++) {
        if (tid == 0) {
            float* co = cent_out + ((size_t)b * GG + it) * 3;
            co[0] = cx; co[1] = cy; co[2] = cz;
            cent_pad[b * GG + it] = make_float4(cx, cy, cz, sq3(cx, cy, cz));
        }
        if (it == GG - 1) break;  // last argmax unused
        const int par = it & 1;

        // distance update + 4-chain local argmax (strict > keeps lowest index per chain)
        float bv0 = -INFINITY, bv1 = -INFINITY, bv2 = -INFINITY, bv3 = -INFINITY;
        int bi0 = 0, bi1 = 0, bi2 = 0, bi3 = 0;
#pragma unroll
        for (int j = 0; j < 8; j++) {
            int nb = 4 * (j * 512 + tid);
#pragma unroll
            for (int t = 0; t < 4; t++) {
                int r = j * 4 + t;
                float dx = __fsub_rn(x[r], cx);
                float dy = __fsub_rn(y[r], cy);
                float dz = __fsub_rn(z[r], cz);
                float d = sq3(dx, dy, dz);
                float dj = fminf(dist[r], d);
                dist[r] = dj;
                int n = nb + t;
                switch (t) {
                    case 0: if (dj > bv0) { bv0 = dj; bi0 = n; } break;
                    case 1: if (dj > bv1) { bv1 = dj; bi1 = n; } break;
                    case 2: if (dj > bv2) { bv2 = dj; bi2 = n; } break;
                    case 3: if (dj > bv3) { bv3 = dj; bi3 = n; } break;
                }
            }
        }
        // merge chains, lowest index wins ties
        float mfv = bv0; int mfi = bi0;
        if (bv1 > mfv || (bv1 == mfv && bi1 < mfi)) { mfv = bv1; mfi = bi1; }
        if (bv2 > mfv || (bv2 == mfv && bi2 < mfi)) { mfv = bv2; mfi = bi2; }
        if (bv3 > mfv || (bv3 == mfv && bi3 < mfi)) { mfv = bv3; mfi = bi3; }

        // wave (64-lane) argmax reduce, lower index wins ties
        float fv = mfv; int fi = mfi;
#pragma unroll
        for (int off = 32; off >= 1; off >>= 1) {
            float ov = __shfl_down(fv, off);
            int oi = __shfl_down(fi, off);
            if (ov > fv || (ov == fv && oi < fi)) { fv = ov; fi = oi; }
        }
        int wfi = __shfl(fi, 0);  // broadcast wave winner index
        // exactly one lane owns point wfi: it deposits key+coords (constant indices only)
        if (mfi == wfi) {
            int jj = (wfi >> 2) - tid;  // = j*512
            int tt = wfi & 3;
            float sx = 0.f, sy = 0.f, sz = 0.f;
#pragma unroll
            for (int j = 0; j < 8; j++) {
                if (jj == j * 512) {
#pragma unroll
                    for (int t = 0; t < 4; t++) {
                        if (tt == t) { sx = x[j * 4 + t]; sy = y[j * 4 + t]; sz = z[j * 4 + t]; }
                    }
                }
            }
            // dist >= 0 so float bits are order-monotone; ~idx -> lowest index wins max
            wkey[par][wid] = ((unsigned long long)__float_as_uint(mfv) << 32) |
                             (unsigned)(0xFFFFFFFFu - (unsigned)mfi);
            wx[par][wid] = sx; wy[par][wid] = sy; wz[par][wid] = sz;
        }
        __syncthreads();  // one barrier/iter: winners visible; prev parity now dead
        // every thread scans the 8 wave winners (broadcast LDS reads, conflict-free)
        unsigned long long bk = wkey[par][0];
        int bw = 0;
#pragma unroll
        for (int w = 1; w < 8; w++) {
            unsigned long long k2 = wkey[par][w];
            if (k2 > bk) { bk = k2; bw = w; }
        }
        cx = wx[par][bw]; cy = wy[par][bw]; cz = wz[par][bw];
        // no second barrier: next iteration writes the OTHER parity's slots, and no wave
        // can reach iteration it+2's deposit into THIS parity without passing iteration
        // it+1's barrier, which requires every wave to have finished this scan.
    }
}

// ---------------- group kernel: dist2 + exact top-64 + MLP + mean + LN ----------------
// Keys are recomputed instead of cached (key[64] live across barriers spilled to
// scratch at VGPR=76). hist/cand overlay saves 8KB LDS.
__global__ __launch_bounds__(256, 6) void group_kernel(
    const float* __restrict__ pts, const float4* __restrict__ cent_pad,
    const float* __restrict__ w1, const float* __restrict__ b1,
    const float* __restrict__ w2t, const float* __restrict__ b2,
    const float* __restrict__ lns, const float* __restrict__ lnb,
    float* __restrict__ tok_out) {
    __shared__ __align__(16) union {
        unsigned hist[NBUCK];              // phase 1-2
        unsigned long long cand[CANDCAP];  // phase 3+ (hist dead after scan)
    } sh;
    __shared__ int selIdx[KK];
    __shared__ float4 localPt[KK];
    __shared__ float w1s[3 * HH];
    __shared__ float b1s[HH];
    __shared__ __align__(16) float hbar[HH];
    __shared__ float partial[256];
    __shared__ float red2[8];
    __shared__ float toks[DD];
    __shared__ int waveSum[4];
    __shared__ unsigned long long wmin[4];
    __shared__ unsigned TA_S;
    __shared__ int cntS;
    __shared__ unsigned long long lastS;
    __shared__ float muS, rstdS;

    const int tid = threadIdx.x;
    // XCD-aware swizzle: each XCD sees only 4 batches' points (768KB -> L2 resident)
    int bid = blockIdx.x;
    int xcd = bid & 7, sub = bid >> 3;
    int b = xcd * 4 + (sub >> 7);
    int g = sub & 127;

    const float* p = pts + (size_t)b * NN * 3;
    const float4* p4 = (const float4*)p;
    float4 c4 = cent_pad[b * GG + g];

    for (int i = tid; i < 3 * HH; i += 256) w1s[i] = w1[i];
    if (tid < HH) b1s[tid] = b1[tid];
    for (int i = tid; i < NBUCK; i += 256) sh.hist[i] = 0;
    if (tid == 0) cntS = 0;
    __syncthreads();

    // ---- pass 1: histogram of 11-bit key prefixes (keys recomputed later, not stored)
    for (int i = 0; i < 16; i++) {
        int t4 = i * 256 + tid;  // quad id; points 4*t4 .. 4*t4+3
        float4 A = p4[3 * t4], B = p4[3 * t4 + 1], C = p4[3 * t4 + 2];
        unsigned k0 = distkey(A.x, A.y, A.z, c4);
        unsigned k1 = distkey(A.w, B.x, B.y, c4);
        unsigned k2 = distkey(B.z, B.w, C.x, c4);
        unsigned k3 = distkey(C.y, C.z, C.w, c4);
        atomicAdd(&sh.hist[k0 >> 21], 1u);
        atomicAdd(&sh.hist[k1 >> 21], 1u);
        atomicAdd(&sh.hist[k2 >> 21], 1u);
        atomicAdd(&sh.hist[k3 >> 21], 1u);
    }
    __syncthreads();

    // ---- find boundary bucket: smallest T with cumcount(<=T) >= 64
    {
        uint4 h0 = ((const uint4*)sh.hist)[tid * 2];
        uint4 h1 = ((const uint4*)sh.hist)[tid * 2 + 1];
        int loc[8] = {(int)h0.x, (int)h0.y, (int)h0.z, (int)h0.w,
                      (int)h1.x, (int)h1.y, (int)h1.z, (int)h1.w};
        int s = 0;
#pragma unroll
        for (int j = 0; j < 8; j++) s += loc[j];
        int lane = tid & 63, wid = tid >> 6;
        int v = s;
#pragma unroll
        for (int off = 1; off < 64; off <<= 1) {
            int o = __shfl_up(v, off);
            if (lane >= off) v += o;
        }
        if (lane == 63) waveSum[wid] = v;
        __syncthreads();
        int base = 0;
        for (int w = 0; w < wid; w++) base += waveSum[w];
        int c = base + v - s;  // exclusive prefix at this thread's first bucket
#pragma unroll
        for (int j = 0; j < 8; j++) {
            if (c < KK && c + loc[j] >= KK) TA_S = (unsigned)(tid * 8 + j);
            c += loc[j];
        }
        __syncthreads();
    }
    unsigned TA = TA_S;

    // ---- pass 2: recompute keys, collect candidates in buckets <= TA (~330 expected)
    for (int i = 0; i < 16; i++) {
        int t4 = i * 256 + tid;
        float4 A = p4[3 * t4], B = p4[3 * t4 + 1], C = p4[3 * t4 + 2];
        unsigned k[4];
        k[0] = distkey(A.x, A.y, A.z, c4);
        k[1] = distkey(A.w, B.x, B.y, c4);
        k[2] = distkey(B.z, B.w, C.x, c4);
        k[3] = distkey(C.y, C.z, C.w, c4);
#pragma unroll
        for (int q = 0; q < 4; q++) {
            if ((k[q] >> 21) <= TA) {
                int pos = atomicAdd(&cntS, 1);
                if (pos < CANDCAP)
                    sh.cand[pos] =
                        ((unsigned long long)k[q] << 32) | (unsigned)(4 * t4 + q);
            }
        }
    }
    __syncthreads();
    int cnt = cntS;  // >= 64 by construction

    if (cnt <= CANDCAP) {
        // ---- exact rank-select of the 64 lexicographically smallest (key,idx)
        for (int c0 = tid; c0 < cnt; c0 += 256) {
            unsigned long long pr = sh.cand[c0];
            int rank = 0;
            for (int j = 0; j < cnt; j++) rank += (sh.cand[j] < pr);
            if (rank < KK) selIdx[rank] = (int)(unsigned)pr;
        }
        __syncthreads();
    } else {
        // ---- pathological fallback (never triggers on real data): exact 64-round
        // min-extraction, keys recomputed each round
        if (tid == 0) lastS = 0ull;
        __syncthreads();
        for (int r = 0; r < KK; r++) {
            unsigned long long last = lastS;
            unsigned long long best = 0xFFFFFFFFFFFFFFFFull;
            for (int i = 0; i < 16; i++) {
                int t4 = i * 256 + tid;
                float4 A = p4[3 * t4], B = p4[3 * t4 + 1], C = p4[3 * t4 + 2];
                unsigned k[4];
                k[0] = distkey(A.x, A.y, A.z, c4);
                k[1] = distkey(A.w, B.x, B.y, c4);
                k[2] = distkey(B.z, B.w, C.x, c4);
                k[3] = distkey(C.y, C.z, C.w, c4);
#pragma unroll
                for (int q = 0; q < 4; q++) {
                    unsigned long long pr =
                        ((unsigned long long)k[q] << 32) | (unsigned)(4 * t4 + q);
                    if ((r == 0 || pr > last) && pr < best) best = pr;
                }
            }
            unsigned blo = (unsigned)best, bhi = (unsigned)(best >> 32);
#pragma unroll
            for (int off = 32; off >= 1; off >>= 1) {
                unsigned olo = __shfl_down(blo, off);
                unsigned ohi = __shfl_down(bhi, off);
                unsigned long long ob = ((unsigned long long)ohi << 32) | olo;
                unsigned long long cur = ((unsigned long long)bhi << 32) | blo;
                if (ob < cur) { blo = olo; bhi = ohi; }
            }
            int lane = tid & 63, wid = tid >> 6;
            if (lane == 0) wmin[wid] = ((unsigned long long)bhi << 32) | blo;
            __syncthreads();
            if (tid == 0) {
                unsigned long long m = wmin[0];
                for (int w = 1; w < 4; w++) if (wmin[w] < m) m = wmin[w];
                selIdx[r] = (int)(unsigned)m;
                lastS = m;
            }
            __syncthreads();
        }
    }

    // ---- gather + local coords
    if (tid < KK) {
        int n = selIdx[tid];
        float px = p[n * 3], py = p[n * 3 + 1], pz = p[n * 3 + 2];
        localPt[tid] = make_float4(px - c4.x, py - c4.y, pz - c4.z, 0.f);
    }
    __syncthreads();
    // ---- layer1 + exact GELU + mean over K (2 threads per feature, 32 pts each)
    {
        int f = tid & 127, half = tid >> 7;
        float wa = w1s[f], wb = w1s[HH + f], wc = w1s[2 * HH + f], bb = b1s[f];
        float s = 0.f;
        for (int k = half * 32; k < half * 32 + 32; k++) {
            float4 lp = localPt[k];
            float a = lp.x * wa + lp.y * wb + lp.z * wc + bb;
            float hh = 0.5f * a * (1.0f + erff(a * 0.70710678118654752440f));
            s += hh;
        }
        partial[tid] = s;
    }
    __syncthreads();
    if (tid < HH) hbar[tid] = (partial[tid] + partial[tid + HH]) * (1.0f / 64.0f);
    __syncthreads();
    // ---- layer2: tokens = hbar @ w2 + b2   (mean commutes with the linear layer)
    for (int f2 = tid; f2 < DD; f2 += 256) {
        const float4* wrow = (const float4*)(w2t + f2 * HH);
        const float4* hb = (const float4*)hbar;
        float acc = b2[f2];
#pragma unroll 8
        for (int q = 0; q < 32; q++) {
            float4 w4 = wrow[q];
            float4 h4 = hb[q];
            acc += h4.x * w4.x + h4.y * w4.y + h4.z * w4.z + h4.w * w4.w;
        }
        toks[f2] = acc;
    }
    __syncthreads();
    // ---- LayerNorm over 384
    {
        float s1 = 0.f, s2 = 0.f;
        for (int f2 = tid; f2 < DD; f2 += 256) {
            float v = toks[f2];
            s1 += v;
            s2 += v * v;
        }
#pragma unroll
        for (int off = 32; off >= 1; off >>= 1) {
            s1 += __shfl_down(s1, off);
            s2 += __shfl_down(s2, off);
        }
        int lane = tid & 63, wid = tid >> 6;
        if (lane == 0) { partial[wid] = s1; red2[wid] = s2; }
        __syncthreads();
        if (tid == 0) {
            float t1 = partial[0] + partial[1] + partial[2] + partial[3];
            float t2 = red2[0] + red2[1] + red2[2] + red2[3];
            float mu = t1 / (float)DD;
            float var = t2 / (float)DD - mu * mu;
            muS = mu;
            rstdS = rsqrtf(var + LN_EPS);
        }
        __syncthreads();
    }
    float mu = muS, rstd = rstdS;
    float* outp = tok_out + ((size_t)b * GG + g) * DD;
    for (int f2 = tid; f2 < DD; f2 += 256) {
        outp[f2] = (toks[f2] - mu) * rstd * lns[f2] + lnb[f2];
    }
}

extern "C" void kernel_launch(void* const* d_in, const int* in_sizes, int n_in,
                              void* d_out, int out_size, void* d_ws, size_t ws_size,
                              hipStream_t stream) {
    const float* pts = (const float*)d_in[0];
    const float* w1 = (const float*)d_in[1];
    const float* b1 = (const float*)d_in[2];
    const float* w2 = (const float*)d_in[3];
    const float* b2 = (const float*)d_in[4];
    const float* lns = (const float*)d_in[5];
    const float* lnb = (const float*)d_in[6];
    float* out = (float*)d_out;

    // ws layout: cent_pad [B*G float4] = 64KB, then w2t [384*128 floats] = 192KB
    float4* cent_pad = (float4*)d_ws;
    float* w2t = (float*)((char*)d_ws + BB * GG * sizeof(float4));

    prep_kernel<<<192, 256, 0, stream>>>(w2, w2t);
    fps_kernel<<<BB, 512, 0, stream>>>(pts, out, cent_pad);
    group_kernel<<<BB * GG, 256, 0, stream>>>(pts, cent_pad, w1, b1, w2t, b2, lns, lnb,
                                              out + BB * GG * 3);
}

// Round 6
// 541.834 us; speedup vs baseline: 3.1685x; 1.0992x over previous
//
#include <hip/hip_runtime.h>
#include <math.h>

#define BB 32
#define NN 16384
#define GG 128
#define KK 64
#define HH 128
#define DD 384
#define LN_EPS 1e-5f
#define NBUCK 2048
#define CANDCAP 1024

// round-to-nearest sum of 3 squares, matching jnp.sum(x**2, -1) order, no FMA contraction
__device__ __forceinline__ float sq3(float x, float y, float z) {
    return __fadd_rn(__fadd_rn(__fmul_rn(x, x), __fmul_rn(y, y)), __fmul_rn(z, z));
}

// order-preserving uint key of dist2, same formula/rounding as reference
__device__ __forceinline__ unsigned distkey(float px, float py, float pz, float4 c4) {
    float p2 = sq3(px, py, pz);
    float dot = __fadd_rn(__fadd_rn(__fmul_rn(c4.x, px), __fmul_rn(c4.y, py)),
                          __fmul_rn(c4.z, pz));
    float d = __fsub_rn(__fadd_rn(c4.w, p2), __fmul_rn(2.0f, dot));
    unsigned u = __float_as_uint(d);
    return u ^ ((u & 0x80000000u) ? 0xFFFFFFFFu : 0x80000000u);
}

// ---------------- prep: transpose w2 [128,384] -> w2t [384,128] ----------------
__global__ void prep_kernel(const float* __restrict__ w2, float* __restrict__ w2t) {
    int i = blockIdx.x * 256 + threadIdx.x;  // over DD*HH = 49152
    if (i < HH * DD) {
        int f = i >> 7;    // 0..383
        int k = i & 127;   // 0..127
        w2t[i] = w2[k * DD + f];
    }
}

// ---------------- FPS: one block per batch, 512 threads, 32 pts/thread ----------------
// Round-5 lesson: the 128-float/thread point cache can't be kept in VGPRs (allocator
// caps at 128 regs; re-streaming from scratch/L2 at 2 waves/SIMD is the ~1.5us/iter
// cost). Fix: stream x,y from LDS instead -- 2 x 64KB packed float4-per-quad, read as
// dense ds_read_b128 (2-way bank aliasing = free). z + dist (64 floats ~ 95 VGPR
// demand) stay in registers, comfortably under even a 128-VGPR cap -> no spills, no
// allocator fight. The 132KB LDS pins occupancy to 1 block/CU by construction.
// LDS pipe (~384 cyc/SIMD/iter) overlaps the VALU work (~1536 cyc/SIMD/iter).
// Tail: proven round-0 per-iteration slot + atomicMax + broadcast winner load.
__global__ __launch_bounds__(512) void fps_kernel(const float* __restrict__ pts,
                                                  float* __restrict__ cent_out,
                                                  float4* __restrict__ cent_pad) {
    __shared__ float4 xl[NN / 4];            // 64KB: x of points 4q..4q+3
    __shared__ float4 yl[NN / 4];            // 64KB: y of points 4q..4q+3
    __shared__ unsigned long long slot[GG];  // one pre-zeroed slot per iteration

    const int b = blockIdx.x;
    const int tid = threadIdx.x;
    const float* p = pts + (size_t)b * NN * 3;
    const float4* p4 = (const float4*)p;

    // thread owns quads q = j*512+tid (j=0..7): points 4q..4q+3, loaded as 3 float4.
    // x,y go to LDS; z,dist stay in registers.
    float z[32], dist[32];
#pragma unroll
    for (int j = 0; j < 8; j++) {
        int q = j * 512 + tid;
        float4 A = p4[3 * q], B = p4[3 * q + 1], C = p4[3 * q + 2];
        xl[q] = make_float4(A.x, A.w, B.z, C.y);
        yl[q] = make_float4(A.y, B.x, B.w, C.z);
        z[j * 4 + 0] = A.z; z[j * 4 + 1] = B.y; z[j * 4 + 2] = C.x; z[j * 4 + 3] = C.w;
#pragma unroll
        for (int t = 0; t < 4; t++) dist[j * 4 + t] = INFINITY;
    }
    for (int i = tid; i < GG; i += 512) slot[i] = 0ull;
    __syncthreads();

    float cx = p[0], cy = p[1], cz = p[2];  // deterministic start at index 0

    for (int it = 0; it < GG; it++) {
        if (tid == 0) {
            float* co = cent_out + ((size_t)b * GG + it) * 3;
            co[0] = cx; co[1] = cy; co[2] = cz;
            cent_pad[b * GG + it] = make_float4(cx, cy, cz, sq3(cx, cy, cz));
        }
        if (it == GG - 1) break;  // last argmax unused

        // distance update + 4-chain local argmax (strict > keeps lowest index per chain)
        float bv0 = -INFINITY, bv1 = -INFINITY, bv2 = -INFINITY, bv3 = -INFINITY;
        int bi0 = 0, bi1 = 0, bi2 = 0, bi3 = 0;
#pragma unroll
        for (int j = 0; j < 8; j++) {
            int q = j * 512 + tid;
            int nb = 4 * q;
            float4 xs = xl[q];  // ds_read_b128, dense (lane i -> bytes 16i)
            float4 ys = yl[q];
            // t = 0
            {
                float dx = __fsub_rn(xs.x, cx);
                float dy = __fsub_rn(ys.x, cy);
                float dz = __fsub_rn(z[j * 4 + 0], cz);
                float d = sq3(dx, dy, dz);
                float dj = fminf(dist[j * 4 + 0], d);
                dist[j * 4 + 0] = dj;
                if (dj > bv0) { bv0 = dj; bi0 = nb + 0; }
            }
            // t = 1
            {
                float dx = __fsub_rn(xs.y, cx);
                float dy = __fsub_rn(ys.y, cy);
                float dz = __fsub_rn(z[j * 4 + 1], cz);
                float d = sq3(dx, dy, dz);
                float dj = fminf(dist[j * 4 + 1], d);
                dist[j * 4 + 1] = dj;
                if (dj > bv1) { bv1 = dj; bi1 = nb + 1; }
            }
            // t = 2
            {
                float dx = __fsub_rn(xs.z, cx);
                float dy = __fsub_rn(ys.z, cy);
                float dz = __fsub_rn(z[j * 4 + 2], cz);
                float d = sq3(dx, dy, dz);
                float dj = fminf(dist[j * 4 + 2], d);
                dist[j * 4 + 2] = dj;
                if (dj > bv2) { bv2 = dj; bi2 = nb + 2; }
            }
            // t = 3
            {
                float dx = __fsub_rn(xs.w, cx);
                float dy = __fsub_rn(ys.w, cy);
                float dz = __fsub_rn(z[j * 4 + 3], cz);
                float d = sq3(dx, dy, dz);
                float dj = fminf(dist[j * 4 + 3], d);
                dist[j * 4 + 3] = dj;
                if (dj > bv3) { bv3 = dj; bi3 = nb + 3; }
            }
        }
        // merge chains, lowest index wins ties
        float fv = bv0; int fi = bi0;
        if (bv1 > fv || (bv1 == fv && bi1 < fi)) { fv = bv1; fi = bi1; }
        if (bv2 > fv || (bv2 == fv && bi2 < fi)) { fv = bv2; fi = bi2; }
        if (bv3 > fv || (bv3 == fv && bi3 < fi)) { fv = bv3; fi = bi3; }
        // wave (64-lane) argmax reduce, lower index wins ties
#pragma unroll
        for (int off = 32; off >= 1; off >>= 1) {
            float ov = __shfl_down(fv, off);
            int oi = __shfl_down(fi, off);
            if (ov > fv || (ov == fv && oi < fi)) { fv = ov; fi = oi; }
        }
        // dist >= 0 so float bits are order-monotone; ~idx -> lowest index wins max
        if ((tid & 63) == 0) {
            unsigned long long packed =
                ((unsigned long long)__float_as_uint(fv) << 32) |
                (unsigned)(0xFFFFFFFFu - (unsigned)fi);
            atomicMax(&slot[it], packed);
        }
        __syncthreads();  // the only barrier per iteration
        unsigned long long w = slot[it];
        int idx = (int)(0xFFFFFFFFu - (unsigned)w);
        const float* wp = p + (size_t)idx * 3;  // broadcast same-address load, L2-hit
        cx = wp[0]; cy = wp[1]; cz = wp[2];
    }
}

// ---------------- group kernel: dist2 + exact top-64 + MLP + mean + LN ----------------
// Keys are recomputed instead of cached (key[64] live across barriers spilled to
// scratch at VGPR=76). hist/cand overlay saves 8KB LDS.
__global__ __launch_bounds__(256, 6) void group_kernel(
    const float* __restrict__ pts, const float4* __restrict__ cent_pad,
    const float* __restrict__ w1, const float* __restrict__ b1,
    const float* __restrict__ w2t, const float* __restrict__ b2,
    const float* __restrict__ lns, const float* __restrict__ lnb,
    float* __restrict__ tok_out) {
    __shared__ __align__(16) union {
        unsigned hist[NBUCK];              // phase 1-2
        unsigned long long cand[CANDCAP];  // phase 3+ (hist dead after scan)
    } sh;
    __shared__ int selIdx[KK];
    __shared__ float4 localPt[KK];
    __shared__ float w1s[3 * HH];
    __shared__ float b1s[HH];
    __shared__ __align__(16) float hbar[HH];
    __shared__ float partial[256];
    __shared__ float red2[8];
    __shared__ float toks[DD];
    __shared__ int waveSum[4];
    __shared__ unsigned long long wmin[4];
    __shared__ unsigned TA_S;
    __shared__ int cntS;
    __shared__ unsigned long long lastS;
    __shared__ float muS, rstdS;

    const int tid = threadIdx.x;
    // XCD-aware swizzle: each XCD sees only 4 batches' points (768KB -> L2 resident)
    int bid = blockIdx.x;
    int xcd = bid & 7, sub = bid >> 3;
    int b = xcd * 4 + (sub >> 7);
    int g = sub & 127;

    const float* p = pts + (size_t)b * NN * 3;
    const float4* p4 = (const float4*)p;
    float4 c4 = cent_pad[b * GG + g];

    for (int i = tid; i < 3 * HH; i += 256) w1s[i] = w1[i];
    if (tid < HH) b1s[tid] = b1[tid];
    for (int i = tid; i < NBUCK; i += 256) sh.hist[i] = 0;
    if (tid == 0) cntS = 0;
    __syncthreads();

    // ---- pass 1: histogram of 11-bit key prefixes (keys recomputed later, not stored)
    for (int i = 0; i < 16; i++) {
        int t4 = i * 256 + tid;  // quad id; points 4*t4 .. 4*t4+3
        float4 A = p4[3 * t4], B = p4[3 * t4 + 1], C = p4[3 * t4 + 2];
        unsigned k0 = distkey(A.x, A.y, A.z, c4);
        unsigned k1 = distkey(A.w, B.x, B.y, c4);
        unsigned k2 = distkey(B.z, B.w, C.x, c4);
        unsigned k3 = distkey(C.y, C.z, C.w, c4);
        atomicAdd(&sh.hist[k0 >> 21], 1u);
        atomicAdd(&sh.hist[k1 >> 21], 1u);
        atomicAdd(&sh.hist[k2 >> 21], 1u);
        atomicAdd(&sh.hist[k3 >> 21], 1u);
    }
    __syncthreads();

    // ---- find boundary bucket: smallest T with cumcount(<=T) >= 64
    {
        uint4 h0 = ((const uint4*)sh.hist)[tid * 2];
        uint4 h1 = ((const uint4*)sh.hist)[tid * 2 + 1];
        int loc[8] = {(int)h0.x, (int)h0.y, (int)h0.z, (int)h0.w,
                      (int)h1.x, (int)h1.y, (int)h1.z, (int)h1.w};
        int s = 0;
#pragma unroll
        for (int j = 0; j < 8; j++) s += loc[j];
        int lane = tid & 63, wid = tid >> 6;
        int v = s;
#pragma unroll
        for (int off = 1; off < 64; off <<= 1) {
            int o = __shfl_up(v, off);
            if (lane >= off) v += o;
        }
        if (lane == 63) waveSum[wid] = v;
        __syncthreads();
        int base = 0;
        for (int w = 0; w < wid; w++) base += waveSum[w];
        int c = base + v - s;  // exclusive prefix at this thread's first bucket
#pragma unroll
        for (int j = 0; j < 8; j++) {
            if (c < KK && c + loc[j] >= KK) TA_S = (unsigned)(tid * 8 + j);
            c += loc[j];
        }
        __syncthreads();
    }
    unsigned TA = TA_S;

    // ---- pass 2: recompute keys, collect candidates in buckets <= TA (~330 expected)
    for (int i = 0; i < 16; i++) {
        int t4 = i * 256 + tid;
        float4 A = p4[3 * t4], B = p4[3 * t4 + 1], C = p4[3 * t4 + 2];
        unsigned k[4];
        k[0] = distkey(A.x, A.y, A.z, c4);
        k[1] = distkey(A.w, B.x, B.y, c4);
        k[2] = distkey(B.z, B.w, C.x, c4);
        k[3] = distkey(C.y, C.z, C.w, c4);
#pragma unroll
        for (int q = 0; q < 4; q++) {
            if ((k[q] >> 21) <= TA) {
                int pos = atomicAdd(&cntS, 1);
                if (pos < CANDCAP)
                    sh.cand[pos] =
                        ((unsigned long long)k[q] << 32) | (unsigned)(4 * t4 + q);
            }
        }
    }
    __syncthreads();
    int cnt = cntS;  // >= 64 by construction

    if (cnt <= CANDCAP) {
        // ---- exact rank-select of the 64 lexicographically smallest (key,idx)
        for (int c0 = tid; c0 < cnt; c0 += 256) {
            unsigned long long pr = sh.cand[c0];
            int rank = 0;
            for (int j = 0; j < cnt; j++) rank += (sh.cand[j] < pr);
            if (rank < KK) selIdx[rank] = (int)(unsigned)pr;
        }
        __syncthreads();
    } else {
        // ---- pathological fallback (never triggers on real data): exact 64-round
        // min-extraction, keys recomputed each round
        if (tid == 0) lastS = 0ull;
        __syncthreads();
        for (int r = 0; r < KK; r++) {
            unsigned long long last = lastS;
            unsigned long long best = 0xFFFFFFFFFFFFFFFFull;
            for (int i = 0; i < 16; i++) {
                int t4 = i * 256 + tid;
                float4 A = p4[3 * t4], B = p4[3 * t4 + 1], C = p4[3 * t4 + 2];
                unsigned k[4];
                k[0] = distkey(A.x, A.y, A.z, c4);
                k[1] = distkey(A.w, B.x, B.y, c4);
                k[2] = distkey(B.z, B.w, C.x, c4);
                k[3] = distkey(C.y, C.z, C.w, c4);
#pragma unroll
                for (int q = 0; q < 4; q++) {
                    unsigned long long pr =
                        ((unsigned long long)k[q] << 32) | (unsigned)(4 * t4 + q);
                    if ((r == 0 || pr > last) && pr < best) best = pr;
                }
            }
            unsigned blo = (unsigned)best, bhi = (unsigned)(best >> 32);
#pragma unroll
            for (int off = 32; off >= 1; off >>= 1) {
                unsigned olo = __shfl_down(blo, off);
                unsigned ohi = __shfl_down(bhi, off);
                unsigned long long ob = ((unsigned long long)ohi << 32) | olo;
                unsigned long long cur = ((unsigned long long)bhi << 32) | blo;
                if (ob < cur) { blo = olo; bhi = ohi; }
            }
            int lane = tid & 63, wid = tid >> 6;
            if (lane == 0) wmin[wid] = ((unsigned long long)bhi << 32) | blo;
            __syncthreads();
            if (tid == 0) {
                unsigned long long m = wmin[0];
                for (int w = 1; w < 4; w++) if (wmin[w] < m) m = wmin[w];
                selIdx[r] = (int)(unsigned)m;
                lastS = m;
            }
            __syncthreads();
        }
    }

    // ---- gather + local coords
    if (tid < KK) {
        int n = selIdx[tid];
        float px = p[n * 3], py = p[n * 3 + 1], pz = p[n * 3 + 2];
        localPt[tid] = make_float4(px - c4.x, py - c4.y, pz - c4.z, 0.f);
    }
    __syncthreads();
    // ---- layer1 + exact GELU + mean over K (2 threads per feature, 32 pts each)
    {
        int f = tid & 127, half = tid >> 7;
        float wa = w1s[f], wb = w1s[HH + f], wc = w1s[2 * HH + f], bb = b1s[f];
        float s = 0.f;
        for (int k = half * 32; k < half * 32 + 32; k++) {
            float4 lp = localPt[k];
            float a = lp.x * wa + lp.y * wb + lp.z * wc + bb;
            float hh = 0.5f * a * (1.0f + erff(a * 0.70710678118654752440f));
            s += hh;
        }
        partial[tid] = s;
    }
    __syncthreads();
    if (tid < HH) hbar[tid] = (partial[tid] + partial[tid + HH]) * (1.0f / 64.0f);
    __syncthreads();
    // ---- layer2: tokens = hbar @ w2 + b2   (mean commutes with the linear layer)
    for (int f2 = tid; f2 < DD; f2 += 256) {
        const float4* wrow = (const float4*)(w2t + f2 * HH);
        const float4* hb = (const float4*)hbar;
        float acc = b2[f2];
#pragma unroll 8
        for (int q = 0; q < 32; q++) {
            float4 w4 = wrow[q];
            float4 h4 = hb[q];
            acc += h4.x * w4.x + h4.y * w4.y + h4.z * w4.z + h4.w * w4.w;
        }
        toks[f2] = acc;
    }
    __syncthreads();
    // ---- LayerNorm over 384
    {
        float s1 = 0.f, s2 = 0.f;
        for (int f2 = tid; f2 < DD; f2 += 256) {
            float v = toks[f2];
            s1 += v;
            s2 += v * v;
        }
#pragma unroll
        for (int off = 32; off >= 1; off >>= 1) {
            s1 += __shfl_down(s1, off);
            s2 += __shfl_down(s2, off);
        }
        int lane = tid & 63, wid = tid >> 6;
        if (lane == 0) { partial[wid] = s1; red2[wid] = s2; }
        __syncthreads();
        if (tid == 0) {
            float t1 = partial[0] + partial[1] + partial[2] + partial[3];
            float t2 = red2[0] + red2[1] + red2[2] + red2[3];
            float mu = t1 / (float)DD;
            float var = t2 / (float)DD - mu * mu;
            muS = mu;
            rstdS = rsqrtf(var + LN_EPS);
        }
        __syncthreads();
    }
    float mu = muS, rstd = rstdS;
    float* outp = tok_out + ((size_t)b * GG + g) * DD;
    for (int f2 = tid; f2 < DD; f2 += 256) {
        outp[f2] = (toks[f2] - mu) * rstd * lns[f2] + lnb[f2];
    }
}

extern "C" void kernel_launch(void* const* d_in, const int* in_sizes, int n_in,
                              void* d_out, int out_size, void* d_ws, size_t ws_size,
                              hipStream_t stream) {
    const float* pts = (const float*)d_in[0];
    const float* w1 = (const float*)d_in[1];
    const float* b1 = (const float*)d_in[2];
    const float* w2 = (const float*)d_in[3];
    const float* b2 = (const float*)d_in[4];
    const float* lns = (const float*)d_in[5];
    const float* lnb = (const float*)d_in[6];
    float* out = (float*)d_out;

    // ws layout: cent_pad [B*G float4] = 64KB, then w2t [384*128 floats] = 192KB
    float4* cent_pad = (float4*)d_ws;
    float* w2t = (float*)((char*)d_ws + BB * GG * sizeof(float4));

    prep_kernel<<<192, 256, 0, stream>>>(w2, w2t);
    fps_kernel<<<BB, 512, 0, stream>>>(pts, out, cent_pad);
    group_kernel<<<BB * GG, 256, 0, stream>>>(pts, cent_pad, w1, b1, w2t, b2, lns, lnb,
                                              out + BB * GG * 3);
}